// Round 1
// baseline (538.493 us; speedup 1.0000x reference)
//
#include <hip/hip_runtime.h>
#include <stdint.h>

#define DEV __device__ __forceinline__

typedef __attribute__((ext_vector_type(8))) short short8;
typedef __attribute__((ext_vector_type(4))) float floatx4;

DEV ushort f2bf(float f) {
  union { float f; uint32_t u; } v; v.f = f;
  uint32_t u = v.u;
  return (ushort)((u + 0x7fffu + ((u >> 16) & 1u)) >> 16);
}

DEV floatx4 zero4() { floatx4 v; v[0] = 0.f; v[1] = 0.f; v[2] = 0.f; v[3] = 0.f; return v; }

// ---------------------------------------------------------------------------
// Cast kernel: x -> bf16, Wc/Wq/Wk/Wv -> bf16, Wo -> bf16 with (qd,h)->(h,qd)
// column permutation so the final GEMM is a standard merged @ Wo'^T.
// grid: (4096, 6) x 256 threads
// ---------------------------------------------------------------------------
__global__ __launch_bounds__(256) void cast_all(
    const float* __restrict__ x,
    const float* __restrict__ Wc, const float* __restrict__ Wq,
    const float* __restrict__ Wk, const float* __restrict__ Wv,
    const float* __restrict__ Wo,
    ushort* __restrict__ xb,
    ushort* __restrict__ Wcb, ushort* __restrict__ Wqb,
    ushort* __restrict__ Wkb, ushort* __restrict__ Wvb,
    ushort* __restrict__ Wob)
{
  const int y = blockIdx.y;
  const int i4 = blockIdx.x * 256 + threadIdx.x;  // 4-element group index
  if (y == 0) {
    if (i4 >= 1048576) return;  // 8192*512/4
    float4 v = ((const float4*)x)[i4];
    ushort4 o;
    o.x = f2bf(v.x); o.y = f2bf(v.y); o.z = f2bf(v.z); o.w = f2bf(v.w);
    *(ushort4*)&xb[i4 * 4] = o;
  } else if (y <= 4) {
    if (i4 >= 65536) return;  // 512*512/4
    const float* s = (y == 1) ? Wc : (y == 2) ? Wq : (y == 3) ? Wk : Wv;
    ushort* d = (y == 1) ? Wcb : (y == 2) ? Wqb : (y == 3) ? Wkb : Wvb;
    float4 v = ((const float4*)s)[i4];
    ushort4 o;
    o.x = f2bf(v.x); o.y = f2bf(v.y); o.z = f2bf(v.z); o.w = f2bf(v.w);
    *(ushort4*)&d[i4 * 4] = o;
  } else {
    if (i4 >= 65536) return;
    // Wob[o][h*64+qd] = Wo[o][qd*8+h]
    int base = i4 * 4;
    #pragma unroll
    for (int k = 0; k < 4; k++) {
      int e = base + k;
      int o = e >> 9;
      int hd = e & 511;
      int h = hd >> 6, qd = hd & 63;
      Wob[e] = f2bf(Wo[o * 512 + qd * 8 + h]);
    }
  }
}

// ---------------------------------------------------------------------------
// bf16 GEMM: C[M,N] = A[M,K] @ W[N,K]^T + bias.  128x128 tile, BK=32,
// 4 waves (2x2), each wave 64x64 via 4x4 grid of 16x16x32 MFMAs.
// LDS tiles padded to stride 40 bf16 (80 B -> 2-way bank aliasing, free).
// ---------------------------------------------------------------------------
template <typename OutT>
__global__ __launch_bounds__(256) void gemm_bias(
    const ushort* __restrict__ A, const ushort* __restrict__ W,
    const float* __restrict__ bias, OutT* __restrict__ C,
    int M, int N, int K)
{
  __shared__ ushort As[128 * 40];
  __shared__ ushort Bs[128 * 40];

  const int t = threadIdx.x;
  const int lane = t & 63, w = t >> 6;
  const int ln = lane & 15, q = lane >> 4;
  const int row0 = blockIdx.y * 128, col0 = blockIdx.x * 128;
  const int wm = w >> 1, wn = w & 1;

  floatx4 acc[4][4];
  #pragma unroll
  for (int i = 0; i < 4; i++)
    #pragma unroll
    for (int j = 0; j < 4; j++) acc[i][j] = zero4();

  for (int k0 = 0; k0 < K; k0 += 32) {
    #pragma unroll
    for (int i = 0; i < 2; i++) {
      int e = t + i * 256;
      int r = e >> 2, s = e & 3;
      *(short8*)&As[r * 40 + s * 8] =
          *(const short8*)&A[(size_t)(row0 + r) * K + k0 + s * 8];
      *(short8*)&Bs[r * 40 + s * 8] =
          *(const short8*)&W[(size_t)(col0 + r) * K + k0 + s * 8];
    }
    __syncthreads();
    short8 af[4], bf[4];
    #pragma unroll
    for (int mi = 0; mi < 4; mi++)
      af[mi] = *(const short8*)&As[(wm * 64 + mi * 16 + ln) * 40 + q * 8];
    #pragma unroll
    for (int ni = 0; ni < 4; ni++)
      bf[ni] = *(const short8*)&Bs[(wn * 64 + ni * 16 + ln) * 40 + q * 8];
    #pragma unroll
    for (int mi = 0; mi < 4; mi++)
      #pragma unroll
      for (int ni = 0; ni < 4; ni++)
        acc[mi][ni] = __builtin_amdgcn_mfma_f32_16x16x32_bf16(
            af[mi], bf[ni], acc[mi][ni], 0, 0, 0);
    __syncthreads();
  }

  #pragma unroll
  for (int mi = 0; mi < 4; mi++)
    #pragma unroll
    for (int ni = 0; ni < 4; ni++) {
      int gcol = col0 + wn * 64 + ni * 16 + ln;
      float bv = bias[gcol];
      #pragma unroll
      for (int r = 0; r < 4; r++) {
        int grow = row0 + wm * 64 + mi * 16 + q * 4 + r;
        float val = acc[mi][ni][r] + bv;
        if constexpr (sizeof(OutT) == 2) {
          C[(size_t)grow * N + gcol] = (OutT)f2bf(val);
        } else {
          C[(size_t)grow * N + gcol] = (OutT)val;
        }
      }
    }
}

// ---------------------------------------------------------------------------
// Fused attention per (b,h,16-row tile): S=QK^T (regs), softmax, write fp32
// scores, P->bf16 in LDS, A=P@V, store merged[b,l,h*64+qd] as bf16.
// 4 waves: wave w owns column subtiles w,w+4 of each 128-j chunk (QK phase)
// and d-dims [w*16, w*16+16) (PV phase).
// ---------------------------------------------------------------------------
__global__ __launch_bounds__(256) void attn(
    const ushort* __restrict__ Qb, const ushort* __restrict__ Kb,
    const ushort* __restrict__ Vb, float* __restrict__ scores,
    ushort* __restrict__ Ab)
{
  __shared__ ushort Qs[16 * 72];     //  2304 B
  __shared__ ushort KVs[128 * 72];   // 18432 B (K chunks, then V chunks)
  __shared__ ushort Ps[16 * 1032];   // 33024 B (probs bf16, padded stride)
  __shared__ float sm[64];
  __shared__ float sl[64];

  const int t = threadIdx.x;
  const int lane = t & 63, w = t >> 6;
  const int ln = lane & 15, q = lane >> 4;
  const int rt = blockIdx.x, pair = blockIdx.y;
  const int b = pair >> 3, h = pair & 7;
  const int l0 = rt * 16;
  const size_t qkvBase = ((size_t)b * 1024) * 512 + h * 64;

  // ---- load Q tile [16 x 64] ----
  if (t < 128) {
    int r = t >> 3, s = t & 7;
    *(short8*)&Qs[r * 72 + s * 8] =
        *(const short8*)&Qb[qkvBase + (size_t)(l0 + r) * 512 + s * 8];
  }
  __syncthreads();
  short8 a0 = *(const short8*)&Qs[ln * 72 + q * 8];        // dims 0..31
  short8 a1 = *(const short8*)&Qs[ln * 72 + 32 + q * 8];   // dims 32..63

  // ---- QK^T: S[16 coltiles][4 rows] in regs ----
  floatx4 S[16];
  #pragma unroll
  for (int i = 0; i < 16; i++) S[i] = zero4();

  for (int ch = 0; ch < 8; ch++) {
    #pragma unroll
    for (int i = 0; i < 4; i++) {
      int e = t + i * 256;
      int r = e >> 3, s = e & 7;
      *(short8*)&KVs[r * 72 + s * 8] =
          *(const short8*)&Kb[qkvBase + (size_t)(ch * 128 + r) * 512 + s * 8];
    }
    __syncthreads();
    #pragma unroll
    for (int sub = 0; sub < 2; sub++) {
      int jr = (w + sub * 4) * 16;
      short8 b0 = *(const short8*)&KVs[(jr + ln) * 72 + q * 8];
      short8 b1 = *(const short8*)&KVs[(jr + ln) * 72 + 32 + q * 8];
      int ct = ch * 2 + sub;
      S[ct] = __builtin_amdgcn_mfma_f32_16x16x32_bf16(a0, b0, S[ct], 0, 0, 0);
      S[ct] = __builtin_amdgcn_mfma_f32_16x16x32_bf16(a1, b1, S[ct], 0, 0, 0);
    }
    __syncthreads();
  }

  // ---- softmax: rows are q*4+r; per-row max over 16 in-lane vals then
  // butterfly over the 16-lane group, then cross-wave via LDS ----
  float mr[4];
  #pragma unroll
  for (int r = 0; r < 4; r++) {
    float m = -3.4e38f;
    #pragma unroll
    for (int ct = 0; ct < 16; ct++) m = fmaxf(m, S[ct][r]);
    #pragma unroll
    for (int off = 1; off < 16; off <<= 1) m = fmaxf(m, __shfl_xor(m, off));
    mr[r] = m;
  }
  if (ln == 0) {
    #pragma unroll
    for (int r = 0; r < 4; r++) sm[w * 16 + q * 4 + r] = mr[r];
  }
  __syncthreads();
  float mfull[4], lsum[4];
  #pragma unroll
  for (int r = 0; r < 4; r++) {
    int row = q * 4 + r;
    mfull[r] = fmaxf(fmaxf(sm[row], sm[16 + row]), fmaxf(sm[32 + row], sm[48 + row]));
    lsum[r] = 0.0f;
  }
  #pragma unroll
  for (int ct = 0; ct < 16; ct++)
    #pragma unroll
    for (int r = 0; r < 4; r++) {
      float e = __expf((S[ct][r] - mfull[r]) * 0.125f);
      S[ct][r] = e;
      lsum[r] += e;
    }
  #pragma unroll
  for (int r = 0; r < 4; r++) {
    #pragma unroll
    for (int off = 1; off < 16; off <<= 1) lsum[r] += __shfl_xor(lsum[r], off);
  }
  if (ln == 0) {
    #pragma unroll
    for (int r = 0; r < 4; r++) sl[w * 16 + q * 4 + r] = lsum[r];
  }
  __syncthreads();
  float rl[4];
  #pragma unroll
  for (int r = 0; r < 4; r++) {
    int row = q * 4 + r;
    rl[r] = 1.0f / (sl[row] + sl[16 + row] + sl[32 + row] + sl[48 + row]);
  }

  // ---- write fp32 scores + bf16 P into LDS ----
  size_t srowBase = ((size_t)pair * 1024 + l0) * 1024;
  #pragma unroll
  for (int ct = 0; ct < 16; ct++) {
    int c0 = (ct >> 1) * 128 + (w + (ct & 1) * 4) * 16;
    #pragma unroll
    for (int r = 0; r < 4; r++) {
      int row = q * 4 + r;
      float p = S[ct][r] * rl[r];
      scores[srowBase + (size_t)row * 1024 + c0 + ln] = p;
      Ps[row * 1032 + c0 + ln] = f2bf(p);
    }
  }
  __syncthreads();

  // ---- PV: wave w owns d-dims [w*16, w*16+16), all j ----
  floatx4 o0 = zero4(), o1 = zero4();
  const int n0 = w * 16;
  for (int ch = 0; ch < 8; ch++) {
    #pragma unroll
    for (int i = 0; i < 4; i++) {
      int e = t + i * 256;
      int r = e >> 3, s = e & 7;
      *(short8*)&KVs[r * 72 + s * 8] =
          *(const short8*)&Vb[qkvBase + (size_t)(ch * 128 + r) * 512 + s * 8];
    }
    __syncthreads();
    #pragma unroll
    for (int kc = 0; kc < 4; kc++) {
      int jb = ch * 128 + kc * 32;  // global j base
      int jl = kc * 32;             // j base within staged chunk
      short8 af = *(const short8*)&Ps[ln * 1032 + jb + q * 8];
      short8 bf;
      #pragma unroll
      for (int jj = 0; jj < 8; jj++)
        bf[jj] = (short)KVs[(jl + q * 8 + jj) * 72 + n0 + ln];
      if (kc & 1)
        o1 = __builtin_amdgcn_mfma_f32_16x16x32_bf16(af, bf, o1, 0, 0, 0);
      else
        o0 = __builtin_amdgcn_mfma_f32_16x16x32_bf16(af, bf, o0, 0, 0, 0);
    }
    __syncthreads();
  }

  // ---- store merged[b, l, h*64 + d] as bf16 ----
  #pragma unroll
  for (int r = 0; r < 4; r++) {
    int row = q * 4 + r;
    float v = o0[r] + o1[r];
    Ab[qkvBase + (size_t)(l0 + row) * 512 + n0 + ln] = f2bf(v);
  }
}

// ---------------------------------------------------------------------------
extern "C" void kernel_launch(void* const* d_in, const int* in_sizes, int n_in,
                              void* d_out, int out_size, void* d_ws, size_t ws_size,
                              hipStream_t stream)
{
  const float* x  = (const float*)d_in[0];
  const float* Wc = (const float*)d_in[1];
  const float* bc = (const float*)d_in[2];
  const float* Wq = (const float*)d_in[3];
  const float* bq = (const float*)d_in[4];
  const float* Wk = (const float*)d_in[5];
  const float* bk = (const float*)d_in[6];
  const float* Wv = (const float*)d_in[7];
  const float* bv = (const float*)d_in[8];
  const float* Wo = (const float*)d_in[9];
  const float* bo = (const float*)d_in[10];

  float* out = (float*)d_out;                       // [8,1024,512]
  float* scores = out + (size_t)8 * 1024 * 512;     // [8,8,1024,1024]

  char* ws = (char*)d_ws;
  const size_t MB8 = (size_t)8 << 20;  // 8 MiB == 8192*512*2 exactly
  ushort* xb  = (ushort*)(ws + 0 * MB8);
  ushort* xr  = (ushort*)(ws + 1 * MB8);
  ushort* Qb  = (ushort*)(ws + 2 * MB8);
  ushort* Kb  = (ushort*)(ws + 3 * MB8);
  ushort* Vb  = (ushort*)(ws + 4 * MB8);
  ushort* Ab  = (ushort*)(ws + 5 * MB8);
  ushort* Wcb = (ushort*)(ws + 6 * MB8);
  ushort* Wqb = (ushort*)(ws + 6 * MB8 + 1 * 524288);
  ushort* Wkb = (ushort*)(ws + 6 * MB8 + 2 * 524288);
  ushort* Wvb = (ushort*)(ws + 6 * MB8 + 3 * 524288);
  ushort* Wob = (ushort*)(ws + 6 * MB8 + 4 * 524288);

  cast_all<<<dim3(4096, 6), 256, 0, stream>>>(x, Wc, Wq, Wk, Wv, Wo,
                                              xb, Wcb, Wqb, Wkb, Wvb, Wob);

  dim3 ggrid(4, 64);  // N/128, M/128
  gemm_bias<ushort><<<ggrid, 256, 0, stream>>>(xb, Wcb, bc, xr, 8192, 512, 512);
  gemm_bias<ushort><<<ggrid, 256, 0, stream>>>(xb, Wqb, bq, Qb, 8192, 512, 512);
  gemm_bias<ushort><<<ggrid, 256, 0, stream>>>(xr, Wkb, bk, Kb, 8192, 512, 512);
  gemm_bias<ushort><<<ggrid, 256, 0, stream>>>(xr, Wvb, bv, Vb, 8192, 512, 512);

  attn<<<dim3(64, 64), 256, 0, stream>>>(Qb, Kb, Vb, scores, Ab);

  gemm_bias<float><<<ggrid, 256, 0, stream>>>(Ab, Wob, bo, out, 8192, 512, 512);
}

// Round 2
// 427.953 us; speedup vs baseline: 1.2583x; 1.2583x over previous
//
#include <hip/hip_runtime.h>
#include <stdint.h>

#define DEV __device__ __forceinline__

typedef __attribute__((ext_vector_type(8))) short short8;
typedef __attribute__((ext_vector_type(4))) float floatx4;

DEV ushort f2bf(float f) {
  union { float f; uint32_t u; } v; v.f = f;
  uint32_t u = v.u;
  return (ushort)((u + 0x7fffu + ((u >> 16) & 1u)) >> 16);
}

DEV float bf2f(ushort u) {
  union { uint32_t u; float f; } v; v.u = ((uint32_t)u) << 16;
  return v.f;
}

DEV floatx4 zero4() { floatx4 v; v[0] = 0.f; v[1] = 0.f; v[2] = 0.f; v[3] = 0.f; return v; }

// ---------------------------------------------------------------------------
// Cast kernel: x -> bf16, Wc/Wq/Wk/Wv -> bf16 (into concatenated W1=[Wc;Wq],
// W2=[Wk;Wv]), Wo -> bf16 with (qd,h)->(h,qd) column permutation.
// grid: (4096, 6) x 256 threads
// ---------------------------------------------------------------------------
__global__ __launch_bounds__(256) void cast_all(
    const float* __restrict__ x,
    const float* __restrict__ Wc, const float* __restrict__ Wq,
    const float* __restrict__ Wk, const float* __restrict__ Wv,
    const float* __restrict__ Wo,
    ushort* __restrict__ xb,
    ushort* __restrict__ Wcb, ushort* __restrict__ Wqb,
    ushort* __restrict__ Wkb, ushort* __restrict__ Wvb,
    ushort* __restrict__ Wob)
{
  const int y = blockIdx.y;
  const int i4 = blockIdx.x * 256 + threadIdx.x;  // 4-element group index
  if (y == 0) {
    if (i4 >= 1048576) return;  // 8192*512/4
    float4 v = ((const float4*)x)[i4];
    ushort4 o;
    o.x = f2bf(v.x); o.y = f2bf(v.y); o.z = f2bf(v.z); o.w = f2bf(v.w);
    *(ushort4*)&xb[i4 * 4] = o;
  } else if (y <= 4) {
    if (i4 >= 65536) return;  // 512*512/4
    const float* s = (y == 1) ? Wc : (y == 2) ? Wq : (y == 3) ? Wk : Wv;
    ushort* d = (y == 1) ? Wcb : (y == 2) ? Wqb : (y == 3) ? Wkb : Wvb;
    float4 v = ((const float4*)s)[i4];
    ushort4 o;
    o.x = f2bf(v.x); o.y = f2bf(v.y); o.z = f2bf(v.z); o.w = f2bf(v.w);
    *(ushort4*)&d[i4 * 4] = o;
  } else {
    if (i4 >= 65536) return;
    // Wob[o][h*64+qd] = Wo[o][qd*8+h]
    int base = i4 * 4;
    #pragma unroll
    for (int k = 0; k < 4; k++) {
      int e = base + k;
      int o = e >> 9;
      int hd = e & 511;
      int h = hd >> 6, qd = hd & 63;
      Wob[e] = f2bf(Wo[o * 512 + qd * 8 + h]);
    }
  }
}

// ---------------------------------------------------------------------------
// bf16 GEMM: C[M,N] = A[M,K=512] @ W[N,512]^T + bias.  64x64 tile, BK=32,
// 256 threads / 4 waves (2x2), each wave 32x32 via 2x2 MFMAs (16x16x32).
// Small tile -> 1024-2048 blocks -> high occupancy (VGPR ~60, LDS 10 KB).
// bias = gcol < 512 ? bias0[gcol] : bias1[gcol-512] (concat outputs).
// ---------------------------------------------------------------------------
template <typename OutT>
__global__ __launch_bounds__(256) void gemm_bias(
    const ushort* __restrict__ A, int lda,
    const ushort* __restrict__ W,
    const float* __restrict__ bias0, const float* __restrict__ bias1,
    OutT* __restrict__ C, int ldc)
{
  __shared__ ushort As[64 * 40];
  __shared__ ushort Bs[64 * 40];

  const int t = threadIdx.x;
  const int lane = t & 63, w = t >> 6;
  const int ln = lane & 15, q = lane >> 4;
  const int row0 = blockIdx.y * 64, col0 = blockIdx.x * 64;
  const int wm = w >> 1, wn = w & 1;

  floatx4 acc[2][2];
  #pragma unroll
  for (int i = 0; i < 2; i++)
    #pragma unroll
    for (int j = 0; j < 2; j++) acc[i][j] = zero4();

  const int sr = t >> 2, ss = t & 3;
  for (int k0 = 0; k0 < 512; k0 += 32) {
    *(short8*)&As[sr * 40 + ss * 8] =
        *(const short8*)&A[(size_t)(row0 + sr) * lda + k0 + ss * 8];
    *(short8*)&Bs[sr * 40 + ss * 8] =
        *(const short8*)&W[(size_t)(col0 + sr) * 512 + k0 + ss * 8];
    __syncthreads();
    short8 af[2], bf[2];
    #pragma unroll
    for (int mi = 0; mi < 2; mi++)
      af[mi] = *(const short8*)&As[(wm * 32 + mi * 16 + ln) * 40 + q * 8];
    #pragma unroll
    for (int ni = 0; ni < 2; ni++)
      bf[ni] = *(const short8*)&Bs[(wn * 32 + ni * 16 + ln) * 40 + q * 8];
    #pragma unroll
    for (int mi = 0; mi < 2; mi++)
      #pragma unroll
      for (int ni = 0; ni < 2; ni++)
        acc[mi][ni] = __builtin_amdgcn_mfma_f32_16x16x32_bf16(
            af[mi], bf[ni], acc[mi][ni], 0, 0, 0);
    __syncthreads();
  }

  #pragma unroll
  for (int mi = 0; mi < 2; mi++)
    #pragma unroll
    for (int ni = 0; ni < 2; ni++) {
      int gcol = col0 + wn * 32 + ni * 16 + ln;
      float bv = (gcol < 512) ? bias0[gcol] : bias1[gcol - 512];
      #pragma unroll
      for (int r = 0; r < 4; r++) {
        int grow = row0 + wm * 32 + mi * 16 + q * 4 + r;
        float val = acc[mi][ni][r] + bv;
        if constexpr (sizeof(OutT) == 2) {
          C[(size_t)grow * ldc + gcol] = (OutT)f2bf(val);
        } else {
          C[(size_t)grow * ldc + gcol] = (OutT)val;
        }
      }
    }
}

// ---------------------------------------------------------------------------
// V transpose: Vt[pair][d][l] <- KV[b*1024+l][512 + h*64 + d]
// grid (16 ltiles, 64 pairs) x 256
// ---------------------------------------------------------------------------
__global__ __launch_bounds__(256) void vtrans(
    const ushort* __restrict__ KV, ushort* __restrict__ Vt)
{
  __shared__ ushort Ts[64 * 72];
  const int t = threadIdx.x;
  const int lt = blockIdx.x, pair = blockIdx.y;
  const int b = pair >> 3, h = pair & 7;
  #pragma unroll
  for (int i = 0; i < 2; i++) {
    int e = t + i * 256;
    int r = e >> 3, s = e & 7;
    *(short8*)&Ts[r * 72 + s * 8] =
        *(const short8*)&KV[((size_t)b * 1024 + lt * 64 + r) * 1024 + 512 + h * 64 + s * 8];
  }
  __syncthreads();
  #pragma unroll
  for (int i = 0; i < 2; i++) {
    int e = t + i * 256;
    int d = e >> 3, s = e & 7;
    short8 o;
    #pragma unroll
    for (int k = 0; k < 8; k++) o[k] = (short)Ts[(s * 8 + k) * 72 + d];
    *(short8*)&Vt[((size_t)pair * 64 + d) * 1024 + lt * 64 + s * 8] = o;
  }
}

// ---------------------------------------------------------------------------
// Fused attention. Block = 32 Q rows x one (b,h); 512 threads = 8 waves as
// 2 row-groups (wr) x 4 col-groups (wc). S = QK^T held in regs (16 tiles x
// 4 f32 per wave), in-wave + cross-wave softmax, then per-128-j-chunk:
// P (bf16) -> LDS, scores (f32) coalesced from LDS, PV MFMA with
// pre-transposed V (contiguous b128 fragment reads).
// grid (32 row-tiles, 64 pairs) x 512
// ---------------------------------------------------------------------------
__global__ __launch_bounds__(512) void attn(
    const ushort* __restrict__ XQ,   // [8192][1024], Q at cols 512+h*64
    const ushort* __restrict__ KV,   // [8192][1024], K at cols h*64
    const ushort* __restrict__ Vt,   // [64 pairs][64 d][1024 l]
    float* __restrict__ scores,
    ushort* __restrict__ Ab)         // [8192][512] merged (h,d)
{
  __shared__ ushort Stage[128 * 72];   // K chunk [128][72] / Vt chunk [64][136]
  __shared__ ushort Ps[32 * 136];      // P chunk bf16
  __shared__ float sm[128];
  __shared__ float sl[128];

  const int t = threadIdx.x;
  const int lane = t & 63, w = t >> 6;
  const int ln = lane & 15, q = lane >> 4;
  const int wr = w >> 2, wc = w & 3;
  const int rt = blockIdx.x, pair = blockIdx.y;
  const int b = pair >> 3, h = pair & 7;
  const int l0 = rt * 32;
  const size_t bRow = (size_t)b * 1024;

  // ---- Q fragments direct from global ----
  const ushort* qrow = &XQ[(bRow + l0 + wr * 16 + ln) * 1024 + 512 + h * 64];
  short8 a0 = *(const short8*)&qrow[q * 8];        // d 0..31
  short8 a1 = *(const short8*)&qrow[32 + q * 8];   // d 32..63

  // ---- QK^T ----
  floatx4 S[16];
  #pragma unroll
  for (int i = 0; i < 16; i++) S[i] = zero4();

  for (int ch = 0; ch < 8; ch++) {
    #pragma unroll
    for (int i = 0; i < 2; i++) {
      int e = t + i * 512;
      int r = e >> 3, s = e & 7;
      *(short8*)&Stage[r * 72 + s * 8] =
          *(const short8*)&KV[(bRow + ch * 128 + r) * 1024 + h * 64 + s * 8];
    }
    __syncthreads();
    #pragma unroll
    for (int sub = 0; sub < 2; sub++) {
      int jr = (wc + sub * 4) * 16;
      short8 b0 = *(const short8*)&Stage[(jr + ln) * 72 + q * 8];
      short8 b1 = *(const short8*)&Stage[(jr + ln) * 72 + 32 + q * 8];
      int ct = ch * 2 + sub;
      S[ct] = __builtin_amdgcn_mfma_f32_16x16x32_bf16(a0, b0, S[ct], 0, 0, 0);
      S[ct] = __builtin_amdgcn_mfma_f32_16x16x32_bf16(a1, b1, S[ct], 0, 0, 0);
    }
    __syncthreads();
  }

  // ---- softmax (rows q*4+r within row-group wr) ----
  float mr[4];
  #pragma unroll
  for (int r = 0; r < 4; r++) {
    float m = -3.4e38f;
    #pragma unroll
    for (int ct = 0; ct < 16; ct++) m = fmaxf(m, S[ct][r]);
    #pragma unroll
    for (int off = 1; off < 16; off <<= 1) m = fmaxf(m, __shfl_xor(m, off));
    mr[r] = m;
  }
  if (ln == 0) {
    #pragma unroll
    for (int r = 0; r < 4; r++) sm[wr * 64 + wc * 16 + q * 4 + r] = mr[r];
  }
  __syncthreads();
  float mfull[4], lsum[4];
  #pragma unroll
  for (int r = 0; r < 4; r++) {
    int base = wr * 64 + q * 4 + r;
    mfull[r] = fmaxf(fmaxf(sm[base], sm[base + 16]),
                     fmaxf(sm[base + 32], sm[base + 48]));
    lsum[r] = 0.0f;
  }
  #pragma unroll
  for (int ct = 0; ct < 16; ct++)
    #pragma unroll
    for (int r = 0; r < 4; r++) {
      float e = __expf((S[ct][r] - mfull[r]) * 0.125f);
      S[ct][r] = e;
      lsum[r] += e;
    }
  #pragma unroll
  for (int r = 0; r < 4; r++) {
    #pragma unroll
    for (int off = 1; off < 16; off <<= 1) lsum[r] += __shfl_xor(lsum[r], off);
  }
  if (ln == 0) {
    #pragma unroll
    for (int r = 0; r < 4; r++) sl[wr * 64 + wc * 16 + q * 4 + r] = lsum[r];
  }
  __syncthreads();
  float rl[4];
  #pragma unroll
  for (int r = 0; r < 4; r++) {
    int base = wr * 64 + q * 4 + r;
    rl[r] = 1.0f / (sl[base] + sl[base + 16] + sl[base + 32] + sl[base + 48]);
  }

  // ---- per-chunk: P->LDS, scores write, PV MFMA ----
  floatx4 O = zero4();
  const int srow = t >> 4;            // scores-write row 0..31
  const int scb = (t & 15) * 8;       // scores-write col base
  for (int ch = 0; ch < 8; ch++) {
    // stage Vt chunk [64 d][128 j] -> Stage stride 136
    #pragma unroll
    for (int i = 0; i < 2; i++) {
      int e = t + i * 512;
      int r = e >> 4, s = e & 15;
      *(short8*)&Stage[r * 136 + s * 8] =
          *(const short8*)&Vt[((size_t)pair * 64 + r) * 1024 + ch * 128 + s * 8];
    }
    // write P chunk from regs
    #pragma unroll
    for (int sub = 0; sub < 2; sub++) {
      int ct = ch * 2 + sub;
      int c0 = (wc + sub * 4) * 16;
      #pragma unroll
      for (int r = 0; r < 4; r++)
        Ps[(wr * 16 + q * 4 + r) * 136 + c0 + ln] = f2bf(S[ct][r] * rl[r]);
    }
    __syncthreads();
    // scores: coalesced f32 from Ps
    {
      short8 pv = *(const short8*)&Ps[srow * 136 + scb];
      size_t so = ((size_t)pair * 1024 + l0 + srow) * 1024 + ch * 128 + scb;
      float4 f0, f1;
      f0.x = bf2f((ushort)pv[0]); f0.y = bf2f((ushort)pv[1]);
      f0.z = bf2f((ushort)pv[2]); f0.w = bf2f((ushort)pv[3]);
      f1.x = bf2f((ushort)pv[4]); f1.y = bf2f((ushort)pv[5]);
      f1.z = bf2f((ushort)pv[6]); f1.w = bf2f((ushort)pv[7]);
      *(float4*)&scores[so] = f0;
      *(float4*)&scores[so + 4] = f1;
    }
    // PV
    #pragma unroll
    for (int kc = 0; kc < 4; kc++) {
      short8 af = *(const short8*)&Ps[(wr * 16 + ln) * 136 + kc * 32 + q * 8];
      short8 bf = *(const short8*)&Stage[(wc * 16 + ln) * 136 + kc * 32 + q * 8];
      O = __builtin_amdgcn_mfma_f32_16x16x32_bf16(af, bf, O, 0, 0, 0);
    }
    __syncthreads();
  }

  // ---- store merged[b, l, h*64 + d] ----
  #pragma unroll
  for (int r = 0; r < 4; r++) {
    Ab[(bRow + l0 + wr * 16 + q * 4 + r) * 512 + h * 64 + wc * 16 + ln] = f2bf(O[r]);
  }
}

// ---------------------------------------------------------------------------
extern "C" void kernel_launch(void* const* d_in, const int* in_sizes, int n_in,
                              void* d_out, int out_size, void* d_ws, size_t ws_size,
                              hipStream_t stream)
{
  const float* x  = (const float*)d_in[0];
  const float* Wc = (const float*)d_in[1];
  const float* bc = (const float*)d_in[2];
  const float* Wq = (const float*)d_in[3];
  const float* bq = (const float*)d_in[4];
  const float* Wk = (const float*)d_in[5];
  const float* bk = (const float*)d_in[6];
  const float* Wv = (const float*)d_in[7];
  const float* bv = (const float*)d_in[8];
  const float* Wo = (const float*)d_in[9];
  const float* bo = (const float*)d_in[10];

  float* out = (float*)d_out;                       // [8,1024,512]
  float* scores = out + (size_t)8 * 1024 * 512;     // [8,8,1024,1024]

  char* ws = (char*)d_ws;
  const size_t MB = (size_t)1 << 20;
  ushort* xb  = (ushort*)(ws + 0);           // 8 MB, reused as Ab after G1
  ushort* Ab  = xb;
  ushort* XQ  = (ushort*)(ws + 8 * MB);      // 16 MB: [8192][1024] = x_r | Q
  ushort* KV  = (ushort*)(ws + 24 * MB);     // 16 MB: [8192][1024] = K | V
  ushort* Vt  = (ushort*)(ws + 40 * MB);     // 8 MB: [64][64][1024]
  ushort* W1  = (ushort*)(ws + 48 * MB);     // 1 MB: [Wc;Wq] bf16
  ushort* W2  = (ushort*)(ws + 49 * MB);     // 1 MB: [Wk;Wv] bf16
  ushort* Wob = (ushort*)(ws + 50 * MB);     // 0.5 MB

  cast_all<<<dim3(4096, 6), 256, 0, stream>>>(
      x, Wc, Wq, Wk, Wv, Wo,
      xb, W1, W1 + 262144, W2, W2 + 262144, Wob);

  // G1: [x_r | Q] = xb @ [Wc;Wq]^T
  gemm_bias<ushort><<<dim3(16, 128), 256, 0, stream>>>(
      xb, 512, W1, bc, bq, XQ, 1024);
  // G2: [K | V] = x_r @ [Wk;Wv]^T
  gemm_bias<ushort><<<dim3(16, 128), 256, 0, stream>>>(
      XQ, 1024, W2, bk, bv, KV, 1024);

  vtrans<<<dim3(16, 64), 256, 0, stream>>>(KV, Vt);

  attn<<<dim3(32, 64), 512, 0, stream>>>(XQ, KV, Vt, scores, Ab);

  // G3: out = merged @ Wob^T
  gemm_bias<float><<<dim3(8, 128), 256, 0, stream>>>(
      Ab, 512, Wob, bo, bo, out, 512);
}